// Round 1
// baseline (633.776 us; speedup 1.0000x reference)
//
#include <hip/hip_runtime.h>
#include <math.h>

#define Bn 16
#define Gn 2048
#define Cn 128
#define Kn 16

// ---------------------------------------------------------------------------
// Kernel 1: KNN top-16 (smallest d2, ties -> lowest index, matching lax.top_k)
// grid 512 = 16 batches x 32 chunks of 64 queries; 256 threads.
// Thread (q = tid&63, sub = tid>>6) scans candidates h = 4*j + sub, j=0..511.
// 4 partial top-16 lists per query merged lexicographically by wave 0.
// ---------------------------------------------------------------------------
__global__ __launch_bounds__(256) void knn_kernel(const float* __restrict__ xyz,
                                                  int* __restrict__ idx_out) {
    __shared__ float4 smem[2080];            // 33,280 B; pts[2048], reused as merge[64*65] float2
    float4* pts = smem;
    float2* mrg = (float2*)smem;

    const int tid   = threadIdx.x;
    const int b     = blockIdx.x >> 5;
    const int chunk = blockIdx.x & 31;

    // stage xyz + precomputed squared norm (reference: sq = sum(xyz*xyz, -1))
    const float* xb = xyz + (size_t)b * Gn * 3;
    for (int i = tid; i < Gn; i += 256) {
        float x = xb[i * 3 + 0], y = xb[i * 3 + 1], z = xb[i * 3 + 2];
        pts[i] = make_float4(x, y, z, x * x + y * y + z * z);
    }
    __syncthreads();

    const int q   = tid & 63;
    const int sub = tid >> 6;
    const int g   = chunk * 64 + q;
    const float4 me = pts[g];
    const float qsq = me.w;

    float bd[16];
    int   bi[16];

    // fill first 16 of my sub-list
    #pragma unroll
    for (int j = 0; j < 16; ++j) {
        int h = 4 * j + sub;
        float4 p = pts[h];
        float dot = me.x * p.x + me.y * p.y + me.z * p.z;
        float d2  = qsq + p.w - 2.0f * dot;   // exact reference formula
        bd[j] = d2; bi[j] = h;
    }
    float maxd = bd[0]; int maxh = bi[0]; int maxp = 0;
    #pragma unroll
    for (int t = 1; t < 16; ++t)
        if (bd[t] > maxd || (bd[t] == maxd && bi[t] > maxh)) { maxd = bd[t]; maxh = bi[t]; maxp = t; }

    // scan remaining candidates (h ascending => strict '<' keeps lowest index on ties)
    for (int j = 16; j < 512; ++j) {
        int h = 4 * j + sub;
        float4 p = pts[h];
        float dot = me.x * p.x + me.y * p.y + me.z * p.z;
        float d2  = qsq + p.w - 2.0f * dot;
        if (d2 < maxd) {
            bd[maxp] = d2; bi[maxp] = h;
            maxd = bd[0]; maxh = bi[0]; maxp = 0;
            #pragma unroll
            for (int t = 1; t < 16; ++t)
                if (bd[t] > maxd || (bd[t] == maxd && bi[t] > maxh)) { maxd = bd[t]; maxh = bi[t]; maxp = t; }
        }
    }
    __syncthreads();   // pts dead; alias LDS as merge scratch

    // publish partial lists: 64 entries per query, row stride 65 (bank-conflict pad)
    #pragma unroll
    for (int t = 0; t < 16; ++t)
        mrg[q * 65 + sub * 16 + t] = make_float2(bd[t], __int_as_float(bi[t]));
    __syncthreads();

    if (sub == 0) {
        // merge the other 3 partial lists into my register list, lexicographic (d2, idx)
        for (int e = 16; e < 64; ++e) {
            float2 en = mrg[q * 65 + e];
            float d = en.x; int h = __float_as_int(en.y);
            if (d < maxd || (d == maxd && h < maxh)) {
                bd[maxp] = d; bi[maxp] = h;
                maxd = bd[0]; maxh = bi[0]; maxp = 0;
                #pragma unroll
                for (int t = 1; t < 16; ++t)
                    if (bd[t] > maxd || (bd[t] == maxd && bi[t] > maxh)) { maxd = bd[t]; maxh = bi[t]; maxp = t; }
            }
        }
        int* op = idx_out + ((size_t)b * Gn + g) * Kn;
        #pragma unroll
        for (int t = 0; t < 16; ++t) op[t] = bi[t];
    }
}

// ---------------------------------------------------------------------------
// Kernel 2: gather neighbor features + L2-norm pool over K
// one wave per query; lane covers channels {2*lane, 2*lane+1} via float2
// ---------------------------------------------------------------------------
__global__ __launch_bounds__(256) void pool_kernel(const float* __restrict__ feat,
                                                   const int* __restrict__ idx,
                                                   float* __restrict__ pooled) {
    const int tid  = threadIdx.x;
    const int lane = tid & 63;
    const int wid  = tid >> 6;
    const int qidx = blockIdx.x * 4 + wid;      // 0..32767
    const int b    = qidx >> 11;

    const int* ip = idx + (size_t)qidx * Kn;
    int hl = ip[lane & 15];                      // lanes 0..15 carry the 16 indices

    const float2* fb = (const float2*)(feat + (size_t)b * Gn * Cn);
    float ax = 0.0f, ay = 0.0f;
    #pragma unroll
    for (int k = 0; k < 16; ++k) {
        int h = __shfl(hl, k);
        float2 f = fb[(size_t)h * 64 + lane];
        ax += f.x * f.x;
        ay += f.y * f.y;
    }
    float2* pp = (float2*)pooled;
    pp[(size_t)qidx * 64 + lane] = make_float2(sqrtf(ax), sqrtf(ay));
}

// ---------------------------------------------------------------------------
// Kernel 3: fused MLP  out = gelu(pooled@W1 + b1) @ W2 + b2   (exact gelu)
// 64 rows per block staged in 32KB LDS; thread = 4 cols (contiguous) x 8 rows
// ---------------------------------------------------------------------------
__device__ __forceinline__ float gelu_exact(float x) {
    return 0.5f * x * (1.0f + erff(x * 0.70710678118654752440f));
}

__global__ __launch_bounds__(256) void mlp_kernel(const float* __restrict__ pooled,
                                                  const float* __restrict__ W1,
                                                  const float* __restrict__ b1,
                                                  const float* __restrict__ W2,
                                                  const float* __restrict__ b2,
                                                  float* __restrict__ out) {
    __shared__ float At[64 * 128];              // 32 KB, reused for hidden activations
    const int tid = threadIdx.x;
    const int j0  = tid & 31;                   // col group: cols 4*j0 .. 4*j0+3
    const int rg  = tid >> 5;                   // row group: rows rg*8 .. rg*8+7
    const int R0  = blockIdx.x * 64;

    // stage 64 pooled rows (coalesced float4)
    const float4* src = (const float4*)(pooled + (size_t)R0 * Cn);
    float4* At4 = (float4*)At;
    for (int t = tid; t < 2048; t += 256) At4[t] = src[t];
    __syncthreads();

    float acc[8][4];

    // ---- layer 1 ----
    {
        const float4* Wv = (const float4*)W1;
        float4 bias = ((const float4*)b1)[j0];
        #pragma unroll
        for (int r = 0; r < 8; ++r) { acc[r][0] = bias.x; acc[r][1] = bias.y; acc[r][2] = bias.z; acc[r][3] = bias.w; }
        for (int i = 0; i < 128; i += 4) {
            float4 wv[4];
            wv[0] = Wv[(i + 0) * 32 + j0];
            wv[1] = Wv[(i + 1) * 32 + j0];
            wv[2] = Wv[(i + 2) * 32 + j0];
            wv[3] = Wv[(i + 3) * 32 + j0];
            #pragma unroll
            for (int r = 0; r < 8; ++r) {
                float4 a = *(const float4*)&At[(rg * 8 + r) * 128 + i];
                float av[4] = {a.x, a.y, a.z, a.w};
                #pragma unroll
                for (int u = 0; u < 4; ++u) {
                    acc[r][0] = fmaf(av[u], wv[u].x, acc[r][0]);
                    acc[r][1] = fmaf(av[u], wv[u].y, acc[r][1]);
                    acc[r][2] = fmaf(av[u], wv[u].z, acc[r][2]);
                    acc[r][3] = fmaf(av[u], wv[u].w, acc[r][3]);
                }
            }
        }
    }
    __syncthreads();                            // everyone done reading At
    #pragma unroll
    for (int r = 0; r < 8; ++r) {
        float4 h;
        h.x = gelu_exact(acc[r][0]); h.y = gelu_exact(acc[r][1]);
        h.z = gelu_exact(acc[r][2]); h.w = gelu_exact(acc[r][3]);
        *(float4*)&At[(rg * 8 + r) * 128 + 4 * j0] = h;
    }
    __syncthreads();

    // ---- layer 2 ----
    {
        const float4* Wv = (const float4*)W2;
        float4 bias = ((const float4*)b2)[j0];
        #pragma unroll
        for (int r = 0; r < 8; ++r) { acc[r][0] = bias.x; acc[r][1] = bias.y; acc[r][2] = bias.z; acc[r][3] = bias.w; }
        for (int i = 0; i < 128; i += 4) {
            float4 wv[4];
            wv[0] = Wv[(i + 0) * 32 + j0];
            wv[1] = Wv[(i + 1) * 32 + j0];
            wv[2] = Wv[(i + 2) * 32 + j0];
            wv[3] = Wv[(i + 3) * 32 + j0];
            #pragma unroll
            for (int r = 0; r < 8; ++r) {
                float4 a = *(const float4*)&At[(rg * 8 + r) * 128 + i];
                float av[4] = {a.x, a.y, a.z, a.w};
                #pragma unroll
                for (int u = 0; u < 4; ++u) {
                    acc[r][0] = fmaf(av[u], wv[u].x, acc[r][0]);
                    acc[r][1] = fmaf(av[u], wv[u].y, acc[r][1]);
                    acc[r][2] = fmaf(av[u], wv[u].z, acc[r][2]);
                    acc[r][3] = fmaf(av[u], wv[u].w, acc[r][3]);
                }
            }
        }
    }
    float4* outv = (float4*)out;
    #pragma unroll
    for (int r = 0; r < 8; ++r)
        outv[((size_t)(R0 + rg * 8 + r)) * 32 + j0] =
            make_float4(acc[r][0], acc[r][1], acc[r][2], acc[r][3]);
}

// ---------------------------------------------------------------------------
extern "C" void kernel_launch(void* const* d_in, const int* in_sizes, int n_in,
                              void* d_out, int out_size, void* d_ws, size_t ws_size,
                              hipStream_t stream) {
    const float* xyz  = (const float*)d_in[0];
    const float* feat = (const float*)d_in[1];
    const float* W1   = (const float*)d_in[2];
    const float* b1   = (const float*)d_in[3];
    const float* W2   = (const float*)d_in[4];
    const float* b2   = (const float*)d_in[5];
    float* out = (float*)d_out;

    int*   idx    = (int*)d_ws;                                        // 2 MB
    float* pooled = (float*)((char*)d_ws + (size_t)Bn * Gn * Kn * 4);  // 16 MB

    knn_kernel <<<512,  256, 0, stream>>>(xyz, idx);
    pool_kernel<<<8192, 256, 0, stream>>>(feat, idx, pooled);
    mlp_kernel <<<512,  256, 0, stream>>>(pooled, W1, b1, W2, b2, out);
}

// Round 2
// 234.566 us; speedup vs baseline: 2.7019x; 2.7019x over previous
//
#include <hip/hip_runtime.h>
#include <math.h>

#define Bn 16
#define Gn 2048
#define Cn 128
#define Kn 16

// ---------------------------------------------------------------------------
// median-of-3 -> v_med3_f32 (1 VALU op)
// ---------------------------------------------------------------------------
__device__ __forceinline__ float med3f(float a, float b, float c) {
#if __has_builtin(__builtin_amdgcn_fmed3f)
    return __builtin_amdgcn_fmed3f(a, b, c);
#else
    return fmaxf(fminf(a, b), fminf(fmaxf(a, b), c));
#endif
}

// exact reference formula: d2 = |q|^2 + |p|^2 - 2<q,p>  (same expression in
// both passes so equality compares are bitwise-consistent)
__device__ __forceinline__ float dist2(const float4 me, const float4 p) {
    float dot = me.x * p.x + me.y * p.y + me.z * p.z;
    return (me.w + p.w) - 2.0f * dot;
}

// ---------------------------------------------------------------------------
// Kernel 1: KNN top-16, branchless med3 insertion (distances only) + rescan.
// grid 1024 = 16 batches x 64 chunks of 32 queries; 256 threads.
// thread = (q = tid&31, sub = tid>>5); sub scans candidates [sub*256, sub*256+256).
// Output is the SET of 16 nearest indices (pooling is order-invariant);
// ties at the threshold resolved lowest-index-first (lax.top_k semantics).
// ---------------------------------------------------------------------------
__global__ __launch_bounds__(256) void knn_kernel(const float* __restrict__ xyz,
                                                  int* __restrict__ idx_out) {
    __shared__ float4 pts[Gn];             // 32 KB: xyz + |p|^2
    __shared__ float  lists[32 * 129];     // 16.5 KB: 8 sorted d[16] per query (pad->no bank conflict)
    __shared__ float  Tq[32];              // per-query 16th-smallest distance

    // aliases into `lists` (dead after merge): append buffers for pass 2
    int* outb  = (int*)lists;              // [32][16]
    int* tieb  = (int*)lists + 512;        // [32][16]
    int* cnt   = (int*)lists + 1024;       // [32]
    int* tcnt  = (int*)lists + 1056;       // [32]

    const int tid   = threadIdx.x;
    const int b     = blockIdx.x >> 6;
    const int chunk = blockIdx.x & 63;
    const int q     = tid & 31;
    const int sub   = tid >> 5;
    const int g     = chunk * 32 + q;

    // stage xyz + squared norm
    const float* xb = xyz + (size_t)b * Gn * 3;
    for (int i = tid; i < Gn; i += 256) {
        float x = xb[i * 3 + 0], y = xb[i * 3 + 1], z = xb[i * 3 + 2];
        pts[i] = make_float4(x, y, z, x * x + y * y + z * z);
    }
    __syncthreads();

    const float4 me = pts[g];

    // ---- pass 1: sorted d[16] via branchless med3 chain (static indices only)
    float d[16];
    #pragma unroll
    for (int t = 0; t < 16; ++t) d[t] = INFINITY;

    const int h0 = sub * 256;
    for (int j = 0; j < 256; ++j) {
        float v = dist2(me, pts[h0 + j]);
        float prev = d[0];
        d[0] = fminf(d[0], v);
        #pragma unroll
        for (int t = 1; t < 16; ++t) {
            float cur = d[t];
            d[t] = med3f(v, prev, cur);     // independent per t: reads old d[t-1], d[t]
            prev = cur;
        }
    }

    // publish sub-lists
    #pragma unroll
    for (int t = 0; t < 16; ++t) lists[q * 129 + sub * 16 + t] = d[t];
    __syncthreads();

    // ---- merge: thread q (tid<32) folds the 7 other sorted lists into d[]
    if (tid < 32) {
        for (int s = 1; s < 8; ++s) {
            #pragma unroll
            for (int u = 0; u < 16; ++u) {
                float v = lists[tid * 129 + s * 16 + u];
                float prev = d[0];
                d[0] = fminf(d[0], v);
                #pragma unroll
                for (int t = 1; t < 16; ++t) {
                    float cur = d[t];
                    d[t] = med3f(v, prev, cur);
                    prev = cur;
                }
            }
        }
        Tq[tid] = d[15];                    // exact 16th smallest of all 2048
    }
    __syncthreads();                        // all merge reads of `lists` done
    if (tid < 32) { cnt[tid] = 0; tcnt[tid] = 0; }
    __syncthreads();

    // ---- pass 2: rescan, append survivors (d2 < T definitely in; d2 == T tied)
    const float T = Tq[q];
    for (int j = 0; j < 256; ++j) {
        int h = h0 + j;
        float v = dist2(me, pts[h]);
        if (v < T) {
            int p = atomicAdd(&cnt[q], 1);
            if (p < 16) outb[q * 16 + p] = h;      // #(v<T) <= 15 guaranteed
        } else if (v == T) {
            int p = atomicAdd(&tcnt[q], 1);
            if (p < 16) tieb[q * 16 + p] = h;
        }
    }
    __syncthreads();

    // ---- finalize: fill remaining slots with lowest-index ties
    if (tid < 32) {
        int m = cnt[tid]; if (m > 16) m = 16;
        int r = 16 - m;
        int tc = tcnt[tid]; if (tc > 16) tc = 16;
        for (int s = 0; s < r; ++s) {
            int best = 0x7fffffff, bp = -1;
            for (int u = 0; u < tc; ++u) {
                int vv = tieb[tid * 16 + u];
                if (vv < best) { best = vv; bp = u; }
            }
            if (bp >= 0) { tieb[tid * 16 + bp] = 0x7fffffff; outb[tid * 16 + m + s] = best; }
        }
    }
    __syncthreads();

    // ---- coalesced global write: [B,G,K]
    int* op = idx_out + ((size_t)b * Gn + (size_t)chunk * 32) * Kn;
    for (int t = tid; t < 512; t += 256) op[t] = outb[t];
}

// ---------------------------------------------------------------------------
// Kernel 2: gather neighbor features + L2-norm pool over K (unchanged)
// ---------------------------------------------------------------------------
__global__ __launch_bounds__(256) void pool_kernel(const float* __restrict__ feat,
                                                   const int* __restrict__ idx,
                                                   float* __restrict__ pooled) {
    const int tid  = threadIdx.x;
    const int lane = tid & 63;
    const int wid  = tid >> 6;
    const int qidx = blockIdx.x * 4 + wid;
    const int b    = qidx >> 11;

    const int* ip = idx + (size_t)qidx * Kn;
    int hl = ip[lane & 15];

    const float2* fb = (const float2*)(feat + (size_t)b * Gn * Cn);
    float ax = 0.0f, ay = 0.0f;
    #pragma unroll
    for (int k = 0; k < 16; ++k) {
        int h = __shfl(hl, k);
        float2 f = fb[(size_t)h * 64 + lane];
        ax += f.x * f.x;
        ay += f.y * f.y;
    }
    float2* pp = (float2*)pooled;
    pp[(size_t)qidx * 64 + lane] = make_float2(sqrtf(ax), sqrtf(ay));
}

// ---------------------------------------------------------------------------
// Kernel 3: fused MLP (unchanged)
// ---------------------------------------------------------------------------
__device__ __forceinline__ float gelu_exact(float x) {
    return 0.5f * x * (1.0f + erff(x * 0.70710678118654752440f));
}

__global__ __launch_bounds__(256) void mlp_kernel(const float* __restrict__ pooled,
                                                  const float* __restrict__ W1,
                                                  const float* __restrict__ b1,
                                                  const float* __restrict__ W2,
                                                  const float* __restrict__ b2,
                                                  float* __restrict__ out) {
    __shared__ float At[64 * 128];
    const int tid = threadIdx.x;
    const int j0  = tid & 31;
    const int rg  = tid >> 5;
    const int R0  = blockIdx.x * 64;

    const float4* src = (const float4*)(pooled + (size_t)R0 * Cn);
    float4* At4 = (float4*)At;
    for (int t = tid; t < 2048; t += 256) At4[t] = src[t];
    __syncthreads();

    float acc[8][4];

    {
        const float4* Wv = (const float4*)W1;
        float4 bias = ((const float4*)b1)[j0];
        #pragma unroll
        for (int r = 0; r < 8; ++r) { acc[r][0] = bias.x; acc[r][1] = bias.y; acc[r][2] = bias.z; acc[r][3] = bias.w; }
        for (int i = 0; i < 128; i += 4) {
            float4 wv[4];
            wv[0] = Wv[(i + 0) * 32 + j0];
            wv[1] = Wv[(i + 1) * 32 + j0];
            wv[2] = Wv[(i + 2) * 32 + j0];
            wv[3] = Wv[(i + 3) * 32 + j0];
            #pragma unroll
            for (int r = 0; r < 8; ++r) {
                float4 a = *(const float4*)&At[(rg * 8 + r) * 128 + i];
                float av[4] = {a.x, a.y, a.z, a.w};
                #pragma unroll
                for (int u = 0; u < 4; ++u) {
                    acc[r][0] = fmaf(av[u], wv[u].x, acc[r][0]);
                    acc[r][1] = fmaf(av[u], wv[u].y, acc[r][1]);
                    acc[r][2] = fmaf(av[u], wv[u].z, acc[r][2]);
                    acc[r][3] = fmaf(av[u], wv[u].w, acc[r][3]);
                }
            }
        }
    }
    __syncthreads();
    #pragma unroll
    for (int r = 0; r < 8; ++r) {
        float4 h;
        h.x = gelu_exact(acc[r][0]); h.y = gelu_exact(acc[r][1]);
        h.z = gelu_exact(acc[r][2]); h.w = gelu_exact(acc[r][3]);
        *(float4*)&At[(rg * 8 + r) * 128 + 4 * j0] = h;
    }
    __syncthreads();

    {
        const float4* Wv = (const float4*)W2;
        float4 bias = ((const float4*)b2)[j0];
        #pragma unroll
        for (int r = 0; r < 8; ++r) { acc[r][0] = bias.x; acc[r][1] = bias.y; acc[r][2] = bias.z; acc[r][3] = bias.w; }
        for (int i = 0; i < 128; i += 4) {
            float4 wv[4];
            wv[0] = Wv[(i + 0) * 32 + j0];
            wv[1] = Wv[(i + 1) * 32 + j0];
            wv[2] = Wv[(i + 2) * 32 + j0];
            wv[3] = Wv[(i + 3) * 32 + j0];
            #pragma unroll
            for (int r = 0; r < 8; ++r) {
                float4 a = *(const float4*)&At[(rg * 8 + r) * 128 + i];
                float av[4] = {a.x, a.y, a.z, a.w};
                #pragma unroll
                for (int u = 0; u < 4; ++u) {
                    acc[r][0] = fmaf(av[u], wv[u].x, acc[r][0]);
                    acc[r][1] = fmaf(av[u], wv[u].y, acc[r][1]);
                    acc[r][2] = fmaf(av[u], wv[u].z, acc[r][2]);
                    acc[r][3] = fmaf(av[u], wv[u].w, acc[r][3]);
                }
            }
        }
    }
    float4* outv = (float4*)out;
    #pragma unroll
    for (int r = 0; r < 8; ++r)
        outv[((size_t)(R0 + rg * 8 + r)) * 32 + j0] =
            make_float4(acc[r][0], acc[r][1], acc[r][2], acc[r][3]);
}

// ---------------------------------------------------------------------------
extern "C" void kernel_launch(void* const* d_in, const int* in_sizes, int n_in,
                              void* d_out, int out_size, void* d_ws, size_t ws_size,
                              hipStream_t stream) {
    const float* xyz  = (const float*)d_in[0];
    const float* feat = (const float*)d_in[1];
    const float* W1   = (const float*)d_in[2];
    const float* b1   = (const float*)d_in[3];
    const float* W2   = (const float*)d_in[4];
    const float* b2   = (const float*)d_in[5];
    float* out = (float*)d_out;

    int*   idx    = (int*)d_ws;                                        // 2 MB
    float* pooled = (float*)((char*)d_ws + (size_t)Bn * Gn * Kn * 4);  // 16 MB

    knn_kernel <<<1024, 256, 0, stream>>>(xyz, idx);
    pool_kernel<<<8192, 256, 0, stream>>>(feat, idx, pooled);
    mlp_kernel <<<512,  256, 0, stream>>>(pooled, W1, b1, W2, b2, out);
}

// Round 3
// 215.391 us; speedup vs baseline: 2.9424x; 1.0890x over previous
//
#include <hip/hip_runtime.h>
#include <math.h>

#define Bn 16
#define Gn 2048
#define Cn 128
#define Kn 16

__device__ __forceinline__ float med3f(float a, float b, float c) {
#if __has_builtin(__builtin_amdgcn_fmed3f)
    return __builtin_amdgcn_fmed3f(a, b, c);
#else
    return fmaxf(fminf(a, b), fminf(fmaxf(a, b), c));
#endif
}

// exact same fp sequence in both passes (explicit fmaf -> no contraction drift)
__device__ __forceinline__ float dist2(const float4 me, const float4 p) {
    float dot = fmaf(me.z, p.z, fmaf(me.y, p.y, me.x * p.x));
    return fmaf(-2.0f, dot, me.w + p.w);
}

// branchless sorted-insert: d ascending; new d[t] = med3(v, old d[t-1], old d[t])
__device__ __forceinline__ void ins16(float (&d)[16], float v) {
    float prev = d[0];
    d[0] = fminf(d[0], v);
    #pragma unroll
    for (int t = 1; t < 16; ++t) { float cur = d[t]; d[t] = med3f(v, prev, cur); prev = cur; }
}

// ---------------------------------------------------------------------------
// Kernel 1: KNN top-16. 1024 blocks = 16 b x 64 chunks of 32 queries; 256 thr.
// lane = q_local*8 + sub: the 8 sub-scans of a query live in ONE wave ->
// merge via shfl_xor bitonic min-merge (no LDS lists). Scan order staggered
// by 37*sub for LDS bank spread (top-16 set is scan-order invariant).
// ---------------------------------------------------------------------------
__global__ __launch_bounds__(256) void knn_kernel(const float* __restrict__ xyz,
                                                  int* __restrict__ idx_out) {
    __shared__ float4 pts[Gn];          // 32 KB
    __shared__ int    outb[32 * 16];    // final indices per query
    __shared__ int    tieb[32 * 16];    // tie candidates
    __shared__ int    cnt[32], tcnt[32];

    const int tid   = threadIdx.x;
    const int b     = blockIdx.x >> 6;
    const int chunk = blockIdx.x & 63;
    const int lane  = tid & 63;
    const int w     = tid >> 6;
    const int sub   = lane & 7;
    const int q     = w * 8 + (lane >> 3);   // 0..31
    const int g     = chunk * 32 + q;

    const float* xb = xyz + (size_t)b * Gn * 3;
    for (int i = tid; i < Gn; i += 256) {
        float x = xb[i * 3 + 0], y = xb[i * 3 + 1], z = xb[i * 3 + 2];
        pts[i] = make_float4(x, y, z, x * x + y * y + z * z);
    }
    __syncthreads();

    const float4 me = pts[g];
    const int base = sub << 8;
    const int c    = (37 * sub) & 255;

    // ---- pass 1: per-lane sorted top-16 distances over 256 candidates
    float d[16];
    #pragma unroll
    for (int t = 0; t < 16; ++t) d[t] = INFINITY;

    for (int j = 0; j < 256; j += 4) {
        float4 p0 = pts[base + ((j + 0 + c) & 255)];
        float4 p1 = pts[base + ((j + 1 + c) & 255)];
        float4 p2 = pts[base + ((j + 2 + c) & 255)];
        float4 p3 = pts[base + ((j + 3 + c) & 255)];
        float v0 = dist2(me, p0), v1 = dist2(me, p1);
        float v2 = dist2(me, p2), v3 = dist2(me, p3);
        ins16(d, v0); ins16(d, v1); ins16(d, v2); ins16(d, v3);
    }

    // ---- intra-wave merge across the 8 subs: 3 butterfly stages.
    // exact: min(a[t], b[15-t]) = 16 smallest of union (bitonic), then sort.
    #pragma unroll
    for (int m = 1; m < 8; m <<= 1) {
        float e[16];
        #pragma unroll
        for (int t = 0; t < 16; ++t) e[t] = __shfl_xor(d[t], m);
        float x[16];
        #pragma unroll
        for (int t = 0; t < 16; ++t) x[t] = fminf(d[t], e[15 - t]);
        #pragma unroll
        for (int k = 8; k; k >>= 1) {
            #pragma unroll
            for (int t = 0; t < 16; ++t)
                if (!(t & k)) {
                    float lo = fminf(x[t], x[t + k]);
                    float hi = fmaxf(x[t], x[t + k]);
                    x[t] = lo; x[t + k] = hi;
                }
        }
        #pragma unroll
        for (int t = 0; t < 16; ++t) d[t] = x[t];
    }
    const float T = d[15];               // exact 16th-smallest of all 2048

    // per-query buffers are touched only by this wave -> no block barrier needed
    if (sub == 0) { cnt[q] = 0; tcnt[q] = 0; }

    // ---- pass 2: rescan, collect indices (set semantics; ties lowest-index)
    for (int j = 0; j < 256; ++j) {
        int h = base + ((j + c) & 255);
        float v = dist2(me, pts[h]);
        if (v <= T) {
            if (v < T) { int p = atomicAdd(&cnt[q], 1); if (p < 16) outb[q * 16 + p] = h; }
            else       { int p = atomicAdd(&tcnt[q], 1); if (p < 16) tieb[q * 16 + p] = h; }
        }
    }

    // ---- finalize: fill remaining slots with lowest-index ties (same wave)
    if (sub == 0) {
        int m = cnt[q]; if (m > 16) m = 16;
        int r = 16 - m;
        int tc = tcnt[q]; if (tc > 16) tc = 16;
        for (int s = 0; s < r; ++s) {
            int best = 0x7fffffff, bp = -1;
            for (int u = 0; u < tc; ++u) {
                int vv = tieb[q * 16 + u];
                if (vv < best) { best = vv; bp = u; }
            }
            if (bp >= 0) { tieb[q * 16 + bp] = 0x7fffffff; outb[q * 16 + m + s] = best; }
        }
    }
    __syncthreads();

    int* op = idx_out + ((size_t)b * Gn + (size_t)chunk * 32) * Kn;
    for (int t = tid; t < 512; t += 256) op[t] = outb[t];
}

// ---------------------------------------------------------------------------
// Kernel 2: fused gather+L2pool+MLP. 1024 blocks x 32 queries; 256 threads.
// Phase 1: pool 32 rows into LDS (no pooled HBM round-trip).
// Phase 2: out = gelu(At@W1+b1)@W2+b2 with register-pipelined W loads.
// ---------------------------------------------------------------------------
__device__ __forceinline__ float gelu_exact(float x) {
    return 0.5f * x * (1.0f + erff(x * 0.70710678118654752440f));
}

__global__ __launch_bounds__(256) void pm_kernel(const float* __restrict__ feat,
                                                 const int* __restrict__ idx,
                                                 const float* __restrict__ W1,
                                                 const float* __restrict__ b1,
                                                 const float* __restrict__ W2,
                                                 const float* __restrict__ b2,
                                                 float* __restrict__ out) {
    __shared__ float At[32 * 128];      // 16 KB
    const int tid  = threadIdx.x;
    const int lane = tid & 63;
    const int w    = tid >> 6;
    const int Q0   = blockIdx.x * 32;

    // ---- phase 1: wave w pools queries Q0+w, +4, ... (8 each)
    for (int qq = w; qq < 32; qq += 4) {
        int qidx = Q0 + qq;
        int bb = qidx >> 11;
        const int* ip = idx + (size_t)qidx * Kn;
        int hl = ip[lane & 15];
        const float2* fb = (const float2*)(feat + (size_t)bb * Gn * Cn);
        float ax = 0.0f, ay = 0.0f;
        #pragma unroll
        for (int k = 0; k < 16; ++k) {
            int h = __shfl(hl, k);
            float2 f = fb[(size_t)h * 64 + lane];
            ax = fmaf(f.x, f.x, ax);
            ay = fmaf(f.y, f.y, ay);
        }
        *(float2*)&At[qq * 128 + lane * 2] = make_float2(sqrtf(ax), sqrtf(ay));
    }
    __syncthreads();

    const int j0 = tid & 31;            // cols 4*j0..4*j0+3
    const int rg = tid >> 5;            // rows rg*4..rg*4+3
    float acc[4][4];

    // ---- layer 1 ----
    {
        const float4* Wv = (const float4*)W1;
        float4 bias = ((const float4*)b1)[j0];
        #pragma unroll
        for (int r = 0; r < 4; ++r) { acc[r][0] = bias.x; acc[r][1] = bias.y; acc[r][2] = bias.z; acc[r][3] = bias.w; }
        float4 cw[4];
        #pragma unroll
        for (int u = 0; u < 4; ++u) cw[u] = Wv[u * 32 + j0];
        for (int i = 0; i < 128; i += 4) {
            float4 nw[4];
            int ii = (i + 4) & 127;     // wraps on last iter (dummy, in-bounds)
            #pragma unroll
            for (int u = 0; u < 4; ++u) nw[u] = Wv[(ii + u) * 32 + j0];
            #pragma unroll
            for (int r = 0; r < 4; ++r) {
                float4 a = *(const float4*)&At[(rg * 4 + r) * 128 + i];
                float av[4] = {a.x, a.y, a.z, a.w};
                #pragma unroll
                for (int u = 0; u < 4; ++u) {
                    acc[r][0] = fmaf(av[u], cw[u].x, acc[r][0]);
                    acc[r][1] = fmaf(av[u], cw[u].y, acc[r][1]);
                    acc[r][2] = fmaf(av[u], cw[u].z, acc[r][2]);
                    acc[r][3] = fmaf(av[u], cw[u].w, acc[r][3]);
                }
            }
            #pragma unroll
            for (int u = 0; u < 4; ++u) cw[u] = nw[u];
        }
    }
    __syncthreads();
    #pragma unroll
    for (int r = 0; r < 4; ++r) {
        float4 h;
        h.x = gelu_exact(acc[r][0]); h.y = gelu_exact(acc[r][1]);
        h.z = gelu_exact(acc[r][2]); h.w = gelu_exact(acc[r][3]);
        *(float4*)&At[(rg * 4 + r) * 128 + 4 * j0] = h;
    }
    __syncthreads();

    // ---- layer 2 ----
    {
        const float4* Wv = (const float4*)W2;
        float4 bias = ((const float4*)b2)[j0];
        #pragma unroll
        for (int r = 0; r < 4; ++r) { acc[r][0] = bias.x; acc[r][1] = bias.y; acc[r][2] = bias.z; acc[r][3] = bias.w; }
        float4 cw[4];
        #pragma unroll
        for (int u = 0; u < 4; ++u) cw[u] = Wv[u * 32 + j0];
        for (int i = 0; i < 128; i += 4) {
            float4 nw[4];
            int ii = (i + 4) & 127;
            #pragma unroll
            for (int u = 0; u < 4; ++u) nw[u] = Wv[(ii + u) * 32 + j0];
            #pragma unroll
            for (int r = 0; r < 4; ++r) {
                float4 a = *(const float4*)&At[(rg * 4 + r) * 128 + i];
                float av[4] = {a.x, a.y, a.z, a.w};
                #pragma unroll
                for (int u = 0; u < 4; ++u) {
                    acc[r][0] = fmaf(av[u], cw[u].x, acc[r][0]);
                    acc[r][1] = fmaf(av[u], cw[u].y, acc[r][1]);
                    acc[r][2] = fmaf(av[u], cw[u].z, acc[r][2]);
                    acc[r][3] = fmaf(av[u], cw[u].w, acc[r][3]);
                }
            }
            #pragma unroll
            for (int u = 0; u < 4; ++u) cw[u] = nw[u];
        }
    }
    float4* outv = (float4*)out;
    #pragma unroll
    for (int r = 0; r < 4; ++r)
        outv[((size_t)(Q0 + rg * 4 + r)) * 32 + j0] =
            make_float4(acc[r][0], acc[r][1], acc[r][2], acc[r][3]);
}

// ---------------------------------------------------------------------------
extern "C" void kernel_launch(void* const* d_in, const int* in_sizes, int n_in,
                              void* d_out, int out_size, void* d_ws, size_t ws_size,
                              hipStream_t stream) {
    const float* xyz  = (const float*)d_in[0];
    const float* feat = (const float*)d_in[1];
    const float* W1   = (const float*)d_in[2];
    const float* b1   = (const float*)d_in[3];
    const float* W2   = (const float*)d_in[4];
    const float* b2   = (const float*)d_in[5];
    float* out = (float*)d_out;

    int* idx = (int*)d_ws;   // 2 MB

    knn_kernel<<<1024, 256, 0, stream>>>(xyz, idx);
    pm_kernel <<<1024, 256, 0, stream>>>(feat, idx, W1, b1, W2, b2, out);
}

// Round 4
// 203.616 us; speedup vs baseline: 3.1126x; 1.0578x over previous
//
#include <hip/hip_runtime.h>
#include <math.h>

#define Bn 16
#define Gn 2048
#define Cn 128
#define Kn 16
#define CAP 256   // survivor buffer per query; mean ~64, 4x headroom

__device__ __forceinline__ float med3f(float a, float b, float c) {
#if __has_builtin(__builtin_amdgcn_fmed3f)
    return __builtin_amdgcn_fmed3f(a, b, c);
#else
    return fmaxf(fminf(a, b), fminf(fmaxf(a, b), c));
#endif
}

// BIT-IDENTICAL to R2's expression in every phase (rank-consistency vs ref).
__device__ __forceinline__ float dist2(const float4 me, const float4 p) {
    float dot = fmaf(me.z, p.z, fmaf(me.y, p.y, me.x * p.x));
    return fmaf(-2.0f, dot, me.w + p.w);
}

__device__ __forceinline__ void ins16(float (&d)[16], float v) {
    float prev = d[0];
    d[0] = fminf(d[0], v);
    #pragma unroll
    for (int t = 1; t < 16; ++t) { float cur = d[t]; d[t] = med3f(v, prev, cur); prev = cur; }
}

// merge sorted d[16] across the 8 lanes of a query group (lanes differ in low-3
// bits). Exact bitonic min-merge; all 8 lanes end with identical merged list.
__device__ __forceinline__ void merge8(float (&d)[16]) {
    #pragma unroll
    for (int m = 1; m < 8; m <<= 1) {
        float e[16];
        #pragma unroll
        for (int t = 0; t < 16; ++t) e[t] = __shfl_xor(d[t], m);
        float x[16];
        #pragma unroll
        for (int t = 0; t < 16; ++t) x[t] = fminf(d[t], e[15 - t]);
        #pragma unroll
        for (int k = 8; k; k >>= 1) {
            #pragma unroll
            for (int t = 0; t < 16; ++t)
                if (!(t & k)) {
                    float lo = fminf(x[t], x[t + k]);
                    float hi = fmaxf(x[t], x[t + k]);
                    x[t] = lo; x[t + k] = hi;
                }
        }
        #pragma unroll
        for (int t = 0; t < 16; ++t) d[t] = x[t];
    }
}

// ---------------------------------------------------------------------------
// Kernel 1: KNN top-16 via sample->filter->select.
// 1024 blocks = 16 b x 64 chunks of 32 queries; 256 thr; lane = qgrp*8+sub.
//  A: exact top16 of 512-sample (64/lane) -> conservative threshold T0
//  B: scan 2048 at ~7 ops/pair, append survivors (e <= T0) to ushort buffer
//  C: exact top16 of survivors -> exact T     D: emit index set from buffer
// ---------------------------------------------------------------------------
__global__ __launch_bounds__(256) void knn_kernel(const float* __restrict__ xyz,
                                                  int* __restrict__ idx_out) {
    __shared__ float4 pts[Gn];                    // 32 KB
    __shared__ unsigned short sbuf[32 * CAP];     // 16 KB survivor indices
    __shared__ int scnt[32];
    __shared__ int outb[32 * 16], tieb[32 * 16];
    __shared__ int cnt2[32], tcnt[32];

    const int tid   = threadIdx.x;
    const int b     = blockIdx.x >> 6;
    const int chunk = blockIdx.x & 63;
    const int lane  = tid & 63;
    const int w     = tid >> 6;
    const int sub   = lane & 7;
    const int q     = w * 8 + (lane >> 3);        // 0..31
    const int g     = chunk * 32 + q;

    const float* xb = xyz + (size_t)b * Gn * 3;
    for (int i = tid; i < Gn; i += 256) {
        float x = xb[i * 3 + 0], y = xb[i * 3 + 1], z = xb[i * 3 + 2];
        pts[i] = make_float4(x, y, z, x * x + y * y + z * z);
    }
    __syncthreads();

    const float4 me = pts[g];
    const int base = sub << 8;
    const int c    = (37 * sub) & 255;            // bank stagger (5*sub mod 8 distinct)

    // ---- phase A: top16 of my first 64 staggered candidates
    float d[16];
    #pragma unroll
    for (int t = 0; t < 16; ++t) d[t] = INFINITY;
    for (int j = 0; j < 64; j += 4) {
        float4 p0 = pts[base + ((j + 0 + c) & 255)];
        float4 p1 = pts[base + ((j + 1 + c) & 255)];
        float4 p2 = pts[base + ((j + 2 + c) & 255)];
        float4 p3 = pts[base + ((j + 3 + c) & 255)];
        ins16(d, dist2(me, p0)); ins16(d, dist2(me, p1));
        ins16(d, dist2(me, p2)); ins16(d, dist2(me, p3));
    }
    merge8(d);
    const float T0 = d[15];                       // 16th of 512-sample >= true T

    // ---- phase B: filter scan (wave-private q-buffers; same-wave LDS ordered)
    if (sub == 0) scnt[q] = 0;
    for (int j = 0; j < 256; j += 4) {
        int h0 = base + ((j + 0 + c) & 255);
        int h1 = base + ((j + 1 + c) & 255);
        int h2 = base + ((j + 2 + c) & 255);
        int h3 = base + ((j + 3 + c) & 255);
        float v0 = dist2(me, pts[h0]);
        float v1 = dist2(me, pts[h1]);
        float v2 = dist2(me, pts[h2]);
        float v3 = dist2(me, pts[h3]);
        if (v0 <= T0) { int p = atomicAdd(&scnt[q], 1); if (p < CAP) sbuf[q * CAP + p] = (unsigned short)h0; }
        if (v1 <= T0) { int p = atomicAdd(&scnt[q], 1); if (p < CAP) sbuf[q * CAP + p] = (unsigned short)h1; }
        if (v2 <= T0) { int p = atomicAdd(&scnt[q], 1); if (p < CAP) sbuf[q * CAP + p] = (unsigned short)h2; }
        if (v3 <= T0) { int p = atomicAdd(&scnt[q], 1); if (p < CAP) sbuf[q * CAP + p] = (unsigned short)h3; }
    }

    // ---- phase C: exact top16 of survivors (split across the 8 subs)
    int S = scnt[q]; if (S > CAP) S = CAP;        // survivors >= 16 always
    #pragma unroll
    for (int t = 0; t < 16; ++t) d[t] = INFINITY;
    for (int t = sub; t < S; t += 8) {
        int h = sbuf[q * CAP + t];
        ins16(d, dist2(me, pts[h]));
    }
    merge8(d);
    const float T = d[15];                        // exact 16th smallest of 2048

    // ---- phase D: emit index set from survivor buffer
    if (sub == 0) { cnt2[q] = 0; tcnt[q] = 0; }
    for (int t = sub; t < S; t += 8) {
        int h = sbuf[q * CAP + t];
        float v = dist2(me, pts[h]);
        if (v < T)      { int p = atomicAdd(&cnt2[q], 1); if (p < 16) outb[q * 16 + p] = h; }
        else if (v == T){ int p = atomicAdd(&tcnt[q], 1); if (p < 16) tieb[q * 16 + p] = h; }
    }

    // fill remaining slots with lowest-index ties (lax.top_k semantics)
    if (sub == 0) {
        int m = cnt2[q]; if (m > 16) m = 16;
        int r = 16 - m;
        int tc = tcnt[q]; if (tc > 16) tc = 16;
        for (int s = 0; s < r; ++s) {
            int best = 0x7fffffff, bp = -1;
            for (int u = 0; u < tc; ++u) {
                int vv = tieb[q * 16 + u];
                if (vv < best) { best = vv; bp = u; }
            }
            if (bp >= 0) { tieb[q * 16 + bp] = 0x7fffffff; outb[q * 16 + m + s] = best; }
        }
    }
    __syncthreads();

    int* op = idx_out + ((size_t)b * Gn + (size_t)chunk * 32) * Kn;
    for (int t = tid; t < 512; t += 256) op[t] = outb[t];
}

// ---------------------------------------------------------------------------
// Kernel 2: fused gather+L2pool+MLP. 512 blocks x 64 rows; 256 threads.
// XCD swizzle: b = ((x&7)<<1)|(x>>8) -> each XCD's L2 holds 2 batches of feat
// (2 MB < 4 MiB) so the gather is L2-local. Thread tile 8 rows x 4 cols.
// ---------------------------------------------------------------------------
__device__ __forceinline__ float gelu_exact(float x) {
    return 0.5f * x * (1.0f + erff(x * 0.70710678118654752440f));
}

__global__ __launch_bounds__(256) void pm_kernel(const float* __restrict__ feat,
                                                 const int* __restrict__ idx,
                                                 const float* __restrict__ W1,
                                                 const float* __restrict__ b1,
                                                 const float* __restrict__ W2,
                                                 const float* __restrict__ b2,
                                                 float* __restrict__ out) {
    __shared__ float At[64 * 128];                // 32 KB
    const int tid  = threadIdx.x;
    const int lane = tid & 63;
    const int w    = tid >> 6;
    const int x    = blockIdx.x;                  // 0..511
    const int b    = ((x & 7) << 1) | (x >> 8);   // XCD-local batch pairing
    const int ch   = (x >> 3) & 31;
    const int Q0   = ch * 64;                     // row within batch

    // ---- phase 1: gather + L2 pool, 16 queries per wave
    const float2* fb = (const float2*)(feat + (size_t)b * Gn * Cn);
    for (int qq = w; qq < 64; qq += 4) {
        const int* ip = idx + ((size_t)b * Gn + Q0 + qq) * Kn;
        int hl = ip[lane & 15];
        int hs[16];
        #pragma unroll
        for (int k = 0; k < 16; ++k) hs[k] = __shfl(hl, k);
        float2 f[16];
        #pragma unroll
        for (int k = 0; k < 16; ++k) f[k] = fb[(size_t)hs[k] * 64 + lane];
        float ax = 0.0f, ay = 0.0f;
        #pragma unroll
        for (int k = 0; k < 16; ++k) {
            ax = fmaf(f[k].x, f[k].x, ax);
            ay = fmaf(f[k].y, f[k].y, ay);
        }
        *(float2*)&At[qq * 128 + lane * 2] = make_float2(sqrtf(ax), sqrtf(ay));
    }
    __syncthreads();

    const int j0 = tid & 31;                      // cols 4*j0..4*j0+3
    const int rg = tid >> 5;                      // rows rg*8..rg*8+7
    float acc[8][4];

    // ---- layer 1 ----
    {
        const float4* Wv = (const float4*)W1;
        float4 bias = ((const float4*)b1)[j0];
        #pragma unroll
        for (int r = 0; r < 8; ++r) { acc[r][0] = bias.x; acc[r][1] = bias.y; acc[r][2] = bias.z; acc[r][3] = bias.w; }
        float4 cw[4];
        #pragma unroll
        for (int u = 0; u < 4; ++u) cw[u] = Wv[u * 32 + j0];
        for (int i = 0; i < 128; i += 4) {
            float4 nw[4];
            int ii = (i + 4) & 127;
            #pragma unroll
            for (int u = 0; u < 4; ++u) nw[u] = Wv[(ii + u) * 32 + j0];
            #pragma unroll
            for (int r = 0; r < 8; ++r) {
                float4 a = *(const float4*)&At[(rg * 8 + r) * 128 + i];
                float av[4] = {a.x, a.y, a.z, a.w};
                #pragma unroll
                for (int u = 0; u < 4; ++u) {
                    acc[r][0] = fmaf(av[u], cw[u].x, acc[r][0]);
                    acc[r][1] = fmaf(av[u], cw[u].y, acc[r][1]);
                    acc[r][2] = fmaf(av[u], cw[u].z, acc[r][2]);
                    acc[r][3] = fmaf(av[u], cw[u].w, acc[r][3]);
                }
            }
            #pragma unroll
            for (int u = 0; u < 4; ++u) cw[u] = nw[u];
        }
    }
    __syncthreads();
    #pragma unroll
    for (int r = 0; r < 8; ++r) {
        float4 h;
        h.x = gelu_exact(acc[r][0]); h.y = gelu_exact(acc[r][1]);
        h.z = gelu_exact(acc[r][2]); h.w = gelu_exact(acc[r][3]);
        *(float4*)&At[(rg * 8 + r) * 128 + 4 * j0] = h;
    }
    __syncthreads();

    // ---- layer 2 ----
    {
        const float4* Wv = (const float4*)W2;
        float4 bias = ((const float4*)b2)[j0];
        #pragma unroll
        for (int r = 0; r < 8; ++r) { acc[r][0] = bias.x; acc[r][1] = bias.y; acc[r][2] = bias.z; acc[r][3] = bias.w; }
        float4 cw[4];
        #pragma unroll
        for (int u = 0; u < 4; ++u) cw[u] = Wv[u * 32 + j0];
        for (int i = 0; i < 128; i += 4) {
            float4 nw[4];
            int ii = (i + 4) & 127;
            #pragma unroll
            for (int u = 0; u < 4; ++u) nw[u] = Wv[(ii + u) * 32 + j0];
            #pragma unroll
            for (int r = 0; r < 8; ++r) {
                float4 a = *(const float4*)&At[(rg * 8 + r) * 128 + i];
                float av[4] = {a.x, a.y, a.z, a.w};
                #pragma unroll
                for (int u = 0; u < 4; ++u) {
                    acc[r][0] = fmaf(av[u], cw[u].x, acc[r][0]);
                    acc[r][1] = fmaf(av[u], cw[u].y, acc[r][1]);
                    acc[r][2] = fmaf(av[u], cw[u].z, acc[r][2]);
                    acc[r][3] = fmaf(av[u], cw[u].w, acc[r][3]);
                }
            }
            #pragma unroll
            for (int u = 0; u < 4; ++u) cw[u] = nw[u];
        }
    }
    float4* outv = (float4*)out;
    #pragma unroll
    for (int r = 0; r < 8; ++r)
        outv[((size_t)b * Gn + Q0 + rg * 8 + r) * 32 + j0] =
            make_float4(acc[r][0], acc[r][1], acc[r][2], acc[r][3]);
}

// ---------------------------------------------------------------------------
extern "C" void kernel_launch(void* const* d_in, const int* in_sizes, int n_in,
                              void* d_out, int out_size, void* d_ws, size_t ws_size,
                              hipStream_t stream) {
    const float* xyz  = (const float*)d_in[0];
    const float* feat = (const float*)d_in[1];
    const float* W1   = (const float*)d_in[2];
    const float* b1   = (const float*)d_in[3];
    const float* W2   = (const float*)d_in[4];
    const float* b2   = (const float*)d_in[5];
    float* out = (float*)d_out;

    int* idx = (int*)d_ws;   // 2 MB

    knn_kernel<<<1024, 256, 0, stream>>>(xyz, idx);
    pm_kernel <<<512,  256, 0, stream>>>(feat, idx, W1, b1, W2, b2, out);
}

// Round 5
// 199.217 us; speedup vs baseline: 3.1813x; 1.0221x over previous
//
#include <hip/hip_runtime.h>
#include <math.h>

#define Bn 16
#define Gn 2048
#define Cn 128
#define Kn 16
#define CAP 192     // survivor cap per query (mean ~64; P(overflow) ~ 1e-16)
#define CAPS 200    // sbuf row stride in ushorts -> query bases 4 banks apart

__device__ __forceinline__ float med3f(float a, float b, float c) {
#if __has_builtin(__builtin_amdgcn_fmed3f)
    return __builtin_amdgcn_fmed3f(a, b, c);
#else
    return fmaxf(fminf(a, b), fminf(fmaxf(a, b), c));
#endif
}

// BIT-IDENTICAL in every phase (fp-consistent ranking incl. tie detection).
__device__ __forceinline__ float dist2(const float4 me, const float4 p) {
    float dot = fmaf(me.z, p.z, fmaf(me.y, p.y, me.x * p.x));
    return fmaf(-2.0f, dot, me.w + p.w);
}

__device__ __forceinline__ void ins16(float (&d)[16], float v) {
    float prev = d[0];
    d[0] = fminf(d[0], v);
    #pragma unroll
    for (int t = 1; t < 16; ++t) { float cur = d[t]; d[t] = med3f(v, prev, cur); prev = cur; }
}

// exact bitonic min-merge of sorted d[16] across the 8 lanes of a group
__device__ __forceinline__ void merge8(float (&d)[16]) {
    #pragma unroll
    for (int m = 1; m < 8; m <<= 1) {
        float e[16];
        #pragma unroll
        for (int t = 0; t < 16; ++t) e[t] = __shfl_xor(d[t], m);
        float x[16];
        #pragma unroll
        for (int t = 0; t < 16; ++t) x[t] = fminf(d[t], e[15 - t]);
        #pragma unroll
        for (int k = 8; k; k >>= 1) {
            #pragma unroll
            for (int t = 0; t < 16; ++t)
                if (!(t & k)) {
                    float lo = fminf(x[t], x[t + k]);
                    float hi = fmaxf(x[t], x[t + k]);
                    x[t] = lo; x[t + k] = hi;
                }
        }
        #pragma unroll
        for (int t = 0; t < 16; ++t) d[t] = x[t];
    }
}

__device__ __forceinline__ float gelu_exact(float x) {
    return 0.5f * x * (1.0f + erff(x * 0.70710678118654752440f));
}

// ---------------------------------------------------------------------------
// Fully fused: KNN (sample->filter->select) + gather/L2-pool + 2-layer MLP.
// 1024 blocks; b = (x&7)|((x>>3)&1)<<3 (XCD-local batches), chunk = x>>4.
// Block owns 32 queries; knn result stays in LDS (outb) and feeds the gather.
// ---------------------------------------------------------------------------
__global__ __launch_bounds__(256) void fused_kernel(const float* __restrict__ xyz,
                                                    const float* __restrict__ feat,
                                                    const float* __restrict__ W1,
                                                    const float* __restrict__ b1,
                                                    const float* __restrict__ W2,
                                                    const float* __restrict__ b2,
                                                    float* __restrict__ out) {
    __shared__ float4 pts[Gn];                      // 32 KB; aliased by At later
    __shared__ unsigned short sbuf[32 * CAPS];      // 12.5 KB survivors
    __shared__ int outb[32 * 16];                   // 2 KB final indices
    __shared__ int tieb[32 * 16];                   // 2 KB tie candidates
    float* At = reinterpret_cast<float*>(pts);      // [32][132] = 16.9 KB alias

    const int x     = blockIdx.x;
    const int b     = (x & 7) | (((x >> 3) & 1) << 3);
    const int chunk = x >> 4;                       // 0..63
    const int tid   = threadIdx.x;
    const int lane  = tid & 63;
    const int w     = tid >> 6;
    const int sub   = lane & 7;
    const int qg    = lane >> 3;                    // group within wave
    const int q     = w * 8 + qg;                   // 0..31
    const int g     = chunk * 32 + q;

    // ---- stage xyz + |p|^2
    const float* xb = xyz + (size_t)b * Gn * 3;
    for (int i = tid; i < Gn; i += 256) {
        float px = xb[i * 3 + 0], py = xb[i * 3 + 1], pz = xb[i * 3 + 2];
        pts[i] = make_float4(px, py, pz, px * px + py * py + pz * pz);
    }
    __syncthreads();

    const float4 me = pts[g];
    const int base = sub << 8;
    const int c    = (37 * sub) & 255;              // bank stagger

    // ---- phase A: top16 of 512-sample (64/lane) -> conservative T0
    float d[16];
    #pragma unroll
    for (int t = 0; t < 16; ++t) d[t] = INFINITY;
    for (int j = 0; j < 64; j += 4) {
        float4 p0 = pts[base + ((j + 0 + c) & 255)];
        float4 p1 = pts[base + ((j + 1 + c) & 255)];
        float4 p2 = pts[base + ((j + 2 + c) & 255)];
        float4 p3 = pts[base + ((j + 3 + c) & 255)];
        ins16(d, dist2(me, p0)); ins16(d, dist2(me, p1));
        ins16(d, dist2(me, p2)); ins16(d, dist2(me, p3));
    }
    merge8(d);
    const float T0 = d[15];

    // ---- phase B: filter scan, ballot-append (no atomics)
    const unsigned lowm = (1u << sub) - 1;
    const int shft = lane & 56;                     // group base bit
    int cnt = 0;
    for (int j = 0; j < 256; j += 4) {
        int h0 = base + ((j + 0 + c) & 255);
        int h1 = base + ((j + 1 + c) & 255);
        int h2 = base + ((j + 2 + c) & 255);
        int h3 = base + ((j + 3 + c) & 255);
        float v0 = dist2(me, pts[h0]);
        float v1 = dist2(me, pts[h1]);
        float v2 = dist2(me, pts[h2]);
        float v3 = dist2(me, pts[h3]);
        #pragma unroll
        for (int u = 0; u < 4; ++u) {
            float v = (u == 0) ? v0 : (u == 1) ? v1 : (u == 2) ? v2 : v3;
            int   h = (u == 0) ? h0 : (u == 1) ? h1 : (u == 2) ? h2 : h3;
            bool pr = (v <= T0);
            unsigned long long m = __ballot(pr);
            unsigned gm = (unsigned)(m >> shft) & 0xFFu;
            if (pr) {
                int pp = cnt + __popc(gm & lowm);
                if (pp < CAP) sbuf[q * CAPS + pp] = (unsigned short)h;
            }
            cnt += __popc(gm);
        }
    }
    const int S = (cnt > CAP) ? CAP : cnt;          // S >= 16 always

    // ---- phase C: exact top16 of survivors -> exact T
    #pragma unroll
    for (int t = 0; t < 16; ++t) d[t] = INFINITY;
    for (int t = sub; t < S; t += 8) {
        int h = sbuf[q * CAPS + t];
        ins16(d, dist2(me, pts[h]));
    }
    merge8(d);
    const float T = d[15];

    // ---- phase D: emit index set (ballot-append; ties lowest-index-first)
    int nl = 0, nt = 0;
    for (int t = sub; t < S; t += 8) {
        int h = sbuf[q * CAPS + t];
        float v = dist2(me, pts[h]);
        bool pl = (v < T), pt = (v == T);
        unsigned long long ml = __ballot(pl);
        unsigned long long mt = __ballot(pt);
        unsigned gml = (unsigned)(ml >> shft) & 0xFFu;
        unsigned gmt = (unsigned)(mt >> shft) & 0xFFu;
        if (pl) outb[q * 16 + nl + __popc(gml & lowm)] = h;       // nl_total <= 15
        if (pt) { int pp = nt + __popc(gmt & lowm); if (pp < 16) tieb[q * 16 + pp] = h; }
        nl += __popc(gml);
        nt += __popc(gmt);
    }
    if (sub == 0) {
        int mfill = nl;                              // < 16
        int need  = 16 - mfill;
        int tc = (nt > 16) ? 16 : nt;
        for (int s = 0; s < need; ++s) {
            int best = 0x7fffffff, bp = -1;
            for (int u = 0; u < tc; ++u) {
                int vv = tieb[q * 16 + u];
                if (vv < best) { best = vv; bp = u; }
            }
            if (bp >= 0) { tieb[q * 16 + bp] = 0x7fffffff; outb[q * 16 + mfill + s] = best; }
        }
    }
    __syncthreads();                                 // pts dead; outb ready

    // ---- gather + L2 pool: half-wave per query, float4 lanes (512B coalesced)
    const float4* fb4 = (const float4*)(feat + (size_t)b * Gn * Cn);
    const int cl = lane & 31;
    #pragma unroll
    for (int pass = 0; pass < 4; ++pass) {
        int qq = w * 8 + pass * 2 + (lane >> 5);
        float4 a = make_float4(0.f, 0.f, 0.f, 0.f);
        #pragma unroll
        for (int half = 0; half < 2; ++half) {
            int hs[8]; float4 f[8];
            #pragma unroll
            for (int k = 0; k < 8; ++k) hs[k] = outb[qq * 16 + half * 8 + k];
            #pragma unroll
            for (int k = 0; k < 8; ++k) f[k] = fb4[(size_t)hs[k] * 32 + cl];
            #pragma unroll
            for (int k = 0; k < 8; ++k) {
                a.x = fmaf(f[k].x, f[k].x, a.x);
                a.y = fmaf(f[k].y, f[k].y, a.y);
                a.z = fmaf(f[k].z, f[k].z, a.z);
                a.w = fmaf(f[k].w, f[k].w, a.w);
            }
        }
        float4 r = make_float4(sqrtf(a.x), sqrtf(a.y), sqrtf(a.z), sqrtf(a.w));
        *(float4*)&At[qq * 132 + cl * 4] = r;        // row stride 132: no conflicts
    }
    __syncthreads();

    // ---- MLP: thread = 2 rows x 8 cols; W register-pipelined from L1/L2
    const int j0 = tid & 15;                         // float4-col pair j0*2, j0*2+1
    const int rg = tid >> 4;                         // rows rg*2, rg*2+1
    float acc[2][8];

    // ---- layer 1
    {
        const float4* Wv = (const float4*)W1;
        float4 ba = ((const float4*)b1)[j0 * 2];
        float4 bb = ((const float4*)b1)[j0 * 2 + 1];
        #pragma unroll
        for (int r = 0; r < 2; ++r) {
            acc[r][0] = ba.x; acc[r][1] = ba.y; acc[r][2] = ba.z; acc[r][3] = ba.w;
            acc[r][4] = bb.x; acc[r][5] = bb.y; acc[r][6] = bb.z; acc[r][7] = bb.w;
        }
        float4 cw[4][2];
        #pragma unroll
        for (int u = 0; u < 4; ++u) {
            cw[u][0] = Wv[u * 32 + j0 * 2];
            cw[u][1] = Wv[u * 32 + j0 * 2 + 1];
        }
        for (int i = 0; i < 128; i += 4) {
            float4 nw[4][2];
            int ii = (i + 4) & 127;
            #pragma unroll
            for (int u = 0; u < 4; ++u) {
                nw[u][0] = Wv[(ii + u) * 32 + j0 * 2];
                nw[u][1] = Wv[(ii + u) * 32 + j0 * 2 + 1];
            }
            #pragma unroll
            for (int r = 0; r < 2; ++r) {
                float4 a = *(const float4*)&At[(rg * 2 + r) * 132 + i];
                float av[4] = {a.x, a.y, a.z, a.w};
                #pragma unroll
                for (int u = 0; u < 4; ++u) {
                    acc[r][0] = fmaf(av[u], cw[u][0].x, acc[r][0]);
                    acc[r][1] = fmaf(av[u], cw[u][0].y, acc[r][1]);
                    acc[r][2] = fmaf(av[u], cw[u][0].z, acc[r][2]);
                    acc[r][3] = fmaf(av[u], cw[u][0].w, acc[r][3]);
                    acc[r][4] = fmaf(av[u], cw[u][1].x, acc[r][4]);
                    acc[r][5] = fmaf(av[u], cw[u][1].y, acc[r][5]);
                    acc[r][6] = fmaf(av[u], cw[u][1].z, acc[r][6]);
                    acc[r][7] = fmaf(av[u], cw[u][1].w, acc[r][7]);
                }
            }
            #pragma unroll
            for (int u = 0; u < 4; ++u) { cw[u][0] = nw[u][0]; cw[u][1] = nw[u][1]; }
        }
    }
    __syncthreads();
    #pragma unroll
    for (int r = 0; r < 2; ++r) {
        float4 g0, g1;
        g0.x = gelu_exact(acc[r][0]); g0.y = gelu_exact(acc[r][1]);
        g0.z = gelu_exact(acc[r][2]); g0.w = gelu_exact(acc[r][3]);
        g1.x = gelu_exact(acc[r][4]); g1.y = gelu_exact(acc[r][5]);
        g1.z = gelu_exact(acc[r][6]); g1.w = gelu_exact(acc[r][7]);
        *(float4*)&At[(rg * 2 + r) * 132 + j0 * 8]     = g0;
        *(float4*)&At[(rg * 2 + r) * 132 + j0 * 8 + 4] = g1;
    }
    __syncthreads();

    // ---- layer 2
    {
        const float4* Wv = (const float4*)W2;
        float4 ba = ((const float4*)b2)[j0 * 2];
        float4 bb = ((const float4*)b2)[j0 * 2 + 1];
        #pragma unroll
        for (int r = 0; r < 2; ++r) {
            acc[r][0] = ba.x; acc[r][1] = ba.y; acc[r][2] = ba.z; acc[r][3] = ba.w;
            acc[r][4] = bb.x; acc[r][5] = bb.y; acc[r][6] = bb.z; acc[r][7] = bb.w;
        }
        float4 cw[4][2];
        #pragma unroll
        for (int u = 0; u < 4; ++u) {
            cw[u][0] = Wv[u * 32 + j0 * 2];
            cw[u][1] = Wv[u * 32 + j0 * 2 + 1];
        }
        for (int i = 0; i < 128; i += 4) {
            float4 nw[4][2];
            int ii = (i + 4) & 127;
            #pragma unroll
            for (int u = 0; u < 4; ++u) {
                nw[u][0] = Wv[(ii + u) * 32 + j0 * 2];
                nw[u][1] = Wv[(ii + u) * 32 + j0 * 2 + 1];
            }
            #pragma unroll
            for (int r = 0; r < 2; ++r) {
                float4 a = *(const float4*)&At[(rg * 2 + r) * 132 + i];
                float av[4] = {a.x, a.y, a.z, a.w};
                #pragma unroll
                for (int u = 0; u < 4; ++u) {
                    acc[r][0] = fmaf(av[u], cw[u][0].x, acc[r][0]);
                    acc[r][1] = fmaf(av[u], cw[u][0].y, acc[r][1]);
                    acc[r][2] = fmaf(av[u], cw[u][0].z, acc[r][2]);
                    acc[r][3] = fmaf(av[u], cw[u][0].w, acc[r][3]);
                    acc[r][4] = fmaf(av[u], cw[u][1].x, acc[r][4]);
                    acc[r][5] = fmaf(av[u], cw[u][1].y, acc[r][5]);
                    acc[r][6] = fmaf(av[u], cw[u][1].z, acc[r][6]);
                    acc[r][7] = fmaf(av[u], cw[u][1].w, acc[r][7]);
                }
            }
            #pragma unroll
            for (int u = 0; u < 4; ++u) { cw[u][0] = nw[u][0]; cw[u][1] = nw[u][1]; }
        }
    }
    float4* outv = (float4*)out;
    #pragma unroll
    for (int r = 0; r < 2; ++r) {
        size_t row = (size_t)b * Gn + chunk * 32 + rg * 2 + r;
        outv[row * 32 + j0 * 2]     = make_float4(acc[r][0], acc[r][1], acc[r][2], acc[r][3]);
        outv[row * 32 + j0 * 2 + 1] = make_float4(acc[r][4], acc[r][5], acc[r][6], acc[r][7]);
    }
}

// ---------------------------------------------------------------------------
extern "C" void kernel_launch(void* const* d_in, const int* in_sizes, int n_in,
                              void* d_out, int out_size, void* d_ws, size_t ws_size,
                              hipStream_t stream) {
    const float* xyz  = (const float*)d_in[0];
    const float* feat = (const float*)d_in[1];
    const float* W1   = (const float*)d_in[2];
    const float* b1   = (const float*)d_in[3];
    const float* W2   = (const float*)d_in[4];
    const float* b2   = (const float*)d_in[5];
    float* out = (float*)d_out;

    fused_kernel<<<1024, 256, 0, stream>>>(xyz, feat, W1, b1, W2, b2, out);
}